// Round 4
// baseline (139.956 us; speedup 1.0000x reference)
//
#include <hip/hip_runtime.h>
#include <math.h>

#define B_ 16
#define T_ 256
#define NTR_ 1024
#define NTE_ 256
#define K1_ 16
#define LOG2E_ 1.44269504088896340736f
#define INV2PI_ 0.15915494309189533577f

typedef __attribute__((ext_vector_type(2))) float v2f;

// One block per receptive field n (train: 0..1023, test: 1024..1279).
// 256 threads = one t each; all B=16 batches per thread as 8 b-pairs in
// 2-wide vectors (v_pk_fma_f32). All per-k constants force-hoisted from LDS
// into registers before the hot loop (no LDS traffic inside the k-loop).
// __launch_bounds__(256,5): 5 waves/SIMD -> all 5120 waves co-resident.
__global__ __launch_bounds__(256, 5) void decoder_kernel(
    const float* __restrict__ z0,        // (B,T,1)
    const float* __restrict__ z1,        // (B,T,2)
    const float* __restrict__ coeff0,    // (1,1)
    const float* __restrict__ mean0,     // (1,1,1)
    const float* __restrict__ log_var0,  // (1,1,1)
    const float* __restrict__ coeff1,    // (1,16)
    const float* __restrict__ mean1,     // (1,16,2)
    const float* __restrict__ log_var1,  // (1,16,2)
    const float* __restrict__ rf_tr0,    // (NTR,1)
    const float* __restrict__ rf_tr1,    // (NTR,2)
    const float* __restrict__ rf_te0,    // (NTE,1)
    const float* __restrict__ rf_te1,    // (NTE,2)
    const float* __restrict__ ew_tr,     // (NTR,2)
    const float* __restrict__ ew_te,     // (NTE,2)
    const float* __restrict__ lfs_tr,    // (NTR,)
    const float* __restrict__ lfs_te,    // (NTE,)
    float* __restrict__ out)             // out_tr (B,NTR,T) ++ out_te (B,NTE,T)
{
    const int bid = blockIdx.x;
    const int t = threadIdx.x;

    // Select train vs test ensemble (wave-uniform branch)
    const float *rf0, *rf1, *ew, *lfs;
    float* obase;
    int N, n;
    if (bid < NTR_) {
        rf0 = rf_tr0; rf1 = rf_tr1; ew = ew_tr; lfs = lfs_tr;
        obase = out;
        N = NTR_; n = bid;
    } else {
        rf0 = rf_te0; rf1 = rf_te1; ew = ew_te; lfs = lfs_te;
        obase = out + (size_t)B_ * NTR_ * T_;
        N = NTE_; n = bid - NTR_;
    }

    // Per-k euclidean constants in polynomial form with log2(e) folded in:
    //   -log2e*((zx-mux)*ivx)^2 - log2e*((zy-muy)*ivy)^2
    //     = zx*(ax*zx+bx) + zy*(ay*zy+by) + c
    __shared__ float s_ax[K1_], s_bx[K1_], s_ay[K1_], s_by[K1_], s_c[K1_], s_ck[K1_];
    __shared__ float s_sc[8];
    if (t < K1_) {
        float rfx = rf1[n * 2 + 0];
        float rfy = rf1[n * 2 + 1];
        float mux = mean1[t * 2 + 0] - rfx;
        float muy = mean1[t * 2 + 1] - rfy;
        float ivx = __expf(-log_var1[t * 2 + 0]);
        float ivy = __expf(-log_var1[t * 2 + 1]);
        float gx = ivx * ivx * LOG2E_;
        float gy = ivy * ivy * LOG2E_;
        s_ax[t] = -gx;
        s_bx[t] = 2.0f * gx * mux;
        s_ay[t] = -gy;
        s_by[t] = 2.0f * gy * muy;
        s_c[t]  = -gx * mux * mux - gy * muy * muy;
        s_ck[t] = coeff1[t] * LOG2E_;   // resp accumulates in log2 scale
    }
    if (t == 0) {
        // torus (K0=1,L0=1): with v=(sin z,cos z), s=(sin m - sin rf, cos m - cos rf),
        // |v|^2 = 1  =>  -dist0*log2e = Cn + Dn*(v . s)
        float srf = __builtin_amdgcn_sinf(rf0[n] * INV2PI_);
        float crf = __builtin_amdgcn_cosf(rf0[n] * INV2PI_);
        float sm  = __builtin_amdgcn_sinf(mean0[0] * INV2PI_);
        float cm  = __builtin_amdgcn_cosf(mean0[0] * INV2PI_);
        float s0 = sm - srf;
        float s1 = cm - crf;
        float iv = __expf(-log_var0[0]);
        float q = iv * iv * LOG2E_;
        s_sc[0] = s0;
        s_sc[1] = s1;
        s_sc[2] = -q * (1.0f + s0 * s0 + s1 * s1);  // Cn
        s_sc[3] = 2.0f * q;                          // Dn
        s_sc[4] = coeff0[0] * LOG2E_;                // E
        // softmax over the 2 ensemble weights, pre-scaled by exp(lfs)
        float e0 = ew[n * 2 + 0], e1 = ew[n * 2 + 1];
        float mx = fmaxf(e0, e1);
        float x0 = __expf(e0 - mx), x1 = __expf(e1 - mx);
        float elfs = __expf(lfs[n]) / (x0 + x1);
        s_sc[5] = x0 * elfs;   // w0'
        s_sc[6] = x1 * elfs;   // w1'
    }
    __syncthreads();

    // Force-hoist ALL per-k constants LDS -> registers (no LDS in hot loop).
    float cAX[K1_], cBX[K1_], cAY[K1_], cBY[K1_], cC[K1_], cCK[K1_];
#pragma unroll
    for (int k = 0; k < K1_; ++k) {
        cAX[k] = s_ax[k]; cBX[k] = s_bx[k];
        cAY[k] = s_ay[k]; cBY[k] = s_by[k];
        cC[k]  = s_c[k];  cCK[k] = s_ck[k];
    }
    const float s0 = s_sc[0], s1 = s_sc[1], Cn = s_sc[2], Dn = s_sc[3];
    const float E = s_sc[4], w0p = s_sc[5], w1p = s_sc[6];

    // Load all B latent samples for this t as 8 b-pairs (2-wide vectors).
    v2f X[B_ / 2], Y[B_ / 2], R[B_ / 2];
    const float2* z1v = (const float2*)z1;
#pragma unroll
    for (int j = 0; j < B_ / 2; ++j) {
        float2 p0 = z1v[(2 * j + 0) * T_ + t];
        float2 p1 = z1v[(2 * j + 1) * T_ + t];
        X[j] = (v2f){p0.x, p1.x};
        Y[j] = (v2f){p0.y, p1.y};
        R[j] = (v2f){0.0f, 0.0f};
    }

    // k-outer / b-pair-inner: all constants in registers, FMAs packed
#pragma unroll
    for (int k = 0; k < K1_; ++k) {
        v2f AX = {cAX[k], cAX[k]};
        v2f BX = {cBX[k], cBX[k]};
        v2f AY = {cAY[k], cAY[k]};
        v2f BY = {cBY[k], cBY[k]};
        v2f Cc = {cC[k],  cC[k]};
        v2f CK = {cCK[k], cCK[k]};
#pragma unroll
        for (int j = 0; j < B_ / 2; ++j) {
            v2f e = __builtin_elementwise_fma(
                X[j], __builtin_elementwise_fma(X[j], AX, BX),
                __builtin_elementwise_fma(Y[j], __builtin_elementwise_fma(Y[j], AY, BY), Cc));
            v2f ex = {__builtin_amdgcn_exp2f(e.x), __builtin_amdgcn_exp2f(e.y)};
            R[j] = __builtin_elementwise_fma(ex, CK, R[j]);
        }
    }

    const v2f S0 = {s0, s0};
    const v2f S1 = {s1, s1};
    const v2f CN = {Cn, Cn};
    const v2f DN = {Dn, Dn};
    const v2f W0 = {w0p, w0p};
    const v2f W1 = {w1p, w1p};

#pragma unroll
    for (int j = 0; j < B_ / 2; ++j) {
        float a0 = z0[(2 * j + 0) * T_ + t] * INV2PI_;
        float a1 = z0[(2 * j + 1) * T_ + t] * INV2PI_;
        v2f ZS = {__builtin_amdgcn_sinf(a0), __builtin_amdgcn_sinf(a1)};
        v2f ZC = {__builtin_amdgcn_cosf(a0), __builtin_amdgcn_cosf(a1)};
        v2f DOT = __builtin_elementwise_fma(ZC, S1, ZS * S0);
        v2f G = __builtin_elementwise_fma(DOT, DN, CN);
        v2f R0 = {__builtin_amdgcn_exp2f(__builtin_amdgcn_exp2f(G.x) * E),
                  __builtin_amdgcn_exp2f(__builtin_amdgcn_exp2f(G.y) * E)};
        v2f R1 = {__builtin_amdgcn_exp2f(R[j].x), __builtin_amdgcn_exp2f(R[j].y)};
        v2f O = __builtin_elementwise_fma(W0, R0, W1 * R1);
        // write-once stream: bypass L2 residency with non-temporal stores
        __builtin_nontemporal_store(O.x, &obase[(size_t)((2 * j + 0) * N + n) * T_ + t]);
        __builtin_nontemporal_store(O.y, &obase[(size_t)((2 * j + 1) * N + n) * T_ + t]);
    }
}

extern "C" void kernel_launch(void* const* d_in, const int* in_sizes, int n_in,
                              void* d_out, int out_size, void* d_ws, size_t ws_size,
                              hipStream_t stream) {
    const float* z0       = (const float*)d_in[0];
    const float* z1       = (const float*)d_in[1];
    const float* coeff0   = (const float*)d_in[2];
    const float* mean0    = (const float*)d_in[3];
    const float* log_var0 = (const float*)d_in[4];
    const float* coeff1   = (const float*)d_in[5];
    const float* mean1    = (const float*)d_in[6];
    const float* log_var1 = (const float*)d_in[7];
    const float* rf_tr0   = (const float*)d_in[8];
    const float* rf_tr1   = (const float*)d_in[9];
    const float* rf_te0   = (const float*)d_in[10];
    const float* rf_te1   = (const float*)d_in[11];
    const float* ew_tr    = (const float*)d_in[12];
    const float* ew_te    = (const float*)d_in[13];
    const float* lfs_tr   = (const float*)d_in[14];
    const float* lfs_te   = (const float*)d_in[15];
    float* out = (float*)d_out;

    int grid = NTR_ + NTE_;  // 1280 blocks, one per receptive field
    decoder_kernel<<<grid, T_, 0, stream>>>(
        z0, z1, coeff0, mean0, log_var0, coeff1, mean1, log_var1,
        rf_tr0, rf_tr1, rf_te0, rf_te1, ew_tr, ew_te, lfs_tr, lfs_te, out);
}

// Round 5
// 103.467 us; speedup vs baseline: 1.3527x; 1.3527x over previous
//
#include <hip/hip_runtime.h>
#include <math.h>

#define B_ 16
#define T_ 256
#define NTR_ 1024
#define NTE_ 256
#define K1_ 16
#define LOG2E_ 1.44269504088896340736f
#define INV2PI_ 0.15915494309189533577f

typedef __attribute__((ext_vector_type(2))) float v2f;

// One block per receptive field n (train: 0..1023, test: 1024..1279).
// 256 threads = one t each; all B=16 batches per thread as 8 b-pairs in
// 2-wide vectors (v_pk_fma_f32). Per-k constants stay in LDS (broadcast
// reads are free; register-hoisting them under the waves=5 VGPR cap caused
// massive scratch spills in R4 — do NOT hoist). Constants packed so each k
// costs 1 ds_read_b128 + 1 ds_read_b64 instead of 6 ds_read_b32.
// __launch_bounds__(256,5): 5 waves/SIMD -> all 5120 waves co-resident.
__global__ __launch_bounds__(256, 5) void decoder_kernel(
    const float* __restrict__ z0,        // (B,T,1)
    const float* __restrict__ z1,        // (B,T,2)
    const float* __restrict__ coeff0,    // (1,1)
    const float* __restrict__ mean0,     // (1,1,1)
    const float* __restrict__ log_var0,  // (1,1,1)
    const float* __restrict__ coeff1,    // (1,16)
    const float* __restrict__ mean1,     // (1,16,2)
    const float* __restrict__ log_var1,  // (1,16,2)
    const float* __restrict__ rf_tr0,    // (NTR,1)
    const float* __restrict__ rf_tr1,    // (NTR,2)
    const float* __restrict__ rf_te0,    // (NTE,1)
    const float* __restrict__ rf_te1,    // (NTE,2)
    const float* __restrict__ ew_tr,     // (NTR,2)
    const float* __restrict__ ew_te,     // (NTE,2)
    const float* __restrict__ lfs_tr,    // (NTR,)
    const float* __restrict__ lfs_te,    // (NTE,)
    float* __restrict__ out)             // out_tr (B,NTR,T) ++ out_te (B,NTE,T)
{
    const int bid = blockIdx.x;
    const int t = threadIdx.x;

    // Select train vs test ensemble (wave-uniform branch)
    const float *rf0, *rf1, *ew, *lfs;
    float* obase;
    int N, n;
    if (bid < NTR_) {
        rf0 = rf_tr0; rf1 = rf_tr1; ew = ew_tr; lfs = lfs_tr;
        obase = out;
        N = NTR_; n = bid;
    } else {
        rf0 = rf_te0; rf1 = rf_te1; ew = ew_te; lfs = lfs_te;
        obase = out + (size_t)B_ * NTR_ * T_;
        N = NTE_; n = bid - NTR_;
    }

    // Per-k euclidean constants, polynomial form with log2(e) folded in:
    //   -log2e*((zx-mux)*ivx)^2 - log2e*((zy-muy)*ivy)^2
    //     = zx*(ax*zx+bx) + zy*(ay*zy+by) + c
    // Packed: s_q0[k]={ax,bx,ay,by}, s_q1[k]={c,ck}
    __shared__ float4 s_q0[K1_];
    __shared__ float2 s_q1[K1_];
    __shared__ float s_sc[8];
    if (t < K1_) {
        float rfx = rf1[n * 2 + 0];
        float rfy = rf1[n * 2 + 1];
        float mux = mean1[t * 2 + 0] - rfx;
        float muy = mean1[t * 2 + 1] - rfy;
        float ivx = __expf(-log_var1[t * 2 + 0]);
        float ivy = __expf(-log_var1[t * 2 + 1]);
        float gx = ivx * ivx * LOG2E_;
        float gy = ivy * ivy * LOG2E_;
        s_q0[t] = make_float4(-gx, 2.0f * gx * mux, -gy, 2.0f * gy * muy);
        s_q1[t] = make_float2(-gx * mux * mux - gy * muy * muy,
                              coeff1[t] * LOG2E_);  // resp in log2 scale
    }
    if (t == 0) {
        // torus (K0=1,L0=1): with v=(sin z,cos z), s=(sin m - sin rf, cos m - cos rf),
        // |v|^2=1 => -dist0*log2e = Cn + Dn*(v.s), and
        // v.s = s0*sin z + s1*cos z = A*cos(z - phi), A=|s|, phi=atan2(s0,s1)
        float srf = __builtin_amdgcn_sinf(rf0[n] * INV2PI_);
        float crf = __builtin_amdgcn_cosf(rf0[n] * INV2PI_);
        float sm  = __builtin_amdgcn_sinf(mean0[0] * INV2PI_);
        float cm  = __builtin_amdgcn_cosf(mean0[0] * INV2PI_);
        float s0 = sm - srf;
        float s1 = cm - crf;
        float iv = __expf(-log_var0[0]);
        float q = iv * iv * LOG2E_;
        float nrm2 = s0 * s0 + s1 * s1;
        float Cn = -q * (1.0f + nrm2);
        float Dn = 2.0f * q;
        s_sc[0] = sqrtf(nrm2) * Dn;                  // A*Dn
        s_sc[1] = -atan2f(s0, s1) * INV2PI_;         // -phi (revolutions)
        s_sc[2] = Cn;
        s_sc[3] = coeff0[0] * LOG2E_;                // E
        // softmax over the 2 ensemble weights, pre-scaled by exp(lfs)
        float e0 = ew[n * 2 + 0], e1 = ew[n * 2 + 1];
        float mx = fmaxf(e0, e1);
        float x0 = __expf(e0 - mx), x1 = __expf(e1 - mx);
        float elfs = __expf(lfs[n]) / (x0 + x1);
        s_sc[4] = x0 * elfs;   // w0'
        s_sc[5] = x1 * elfs;   // w1'
    }
    __syncthreads();

    // Load all B latent samples for this t as 8 b-pairs (2-wide vectors).
    v2f X[B_ / 2], Y[B_ / 2], R[B_ / 2];
    const float2* z1v = (const float2*)z1;
#pragma unroll
    for (int j = 0; j < B_ / 2; ++j) {
        float2 p0 = z1v[(2 * j + 0) * T_ + t];
        float2 p1 = z1v[(2 * j + 1) * T_ + t];
        X[j] = (v2f){p0.x, p1.x};
        Y[j] = (v2f){p0.y, p1.y};
        R[j] = (v2f){0.0f, 0.0f};
    }

    // k-outer / b-pair-inner: 2 packed LDS reads per k, FMAs packed
#pragma unroll
    for (int k = 0; k < K1_; ++k) {
        float4 q0 = s_q0[k];
        float2 q1 = s_q1[k];
        v2f AX = {q0.x, q0.x};
        v2f BX = {q0.y, q0.y};
        v2f AY = {q0.z, q0.z};
        v2f BY = {q0.w, q0.w};
        v2f Cc = {q1.x, q1.x};
        v2f CK = {q1.y, q1.y};
#pragma unroll
        for (int j = 0; j < B_ / 2; ++j) {
            v2f e = __builtin_elementwise_fma(
                X[j], __builtin_elementwise_fma(X[j], AX, BX),
                __builtin_elementwise_fma(Y[j], __builtin_elementwise_fma(Y[j], AY, BY), Cc));
            v2f ex = {__builtin_amdgcn_exp2f(e.x), __builtin_amdgcn_exp2f(e.y)};
            R[j] = __builtin_elementwise_fma(ex, CK, R[j]);
        }
    }

    const float AD = s_sc[0], MPHI = s_sc[1], Cn = s_sc[2], E = s_sc[3];
    const v2f ADv = {AD, AD};
    const v2f CNv = {Cn, Cn};
    const v2f W0 = {s_sc[4], s_sc[4]};
    const v2f W1 = {s_sc[5], s_sc[5]};

#pragma unroll
    for (int j = 0; j < B_ / 2; ++j) {
        // torus: G = A*Dn*cos(z - phi) + Cn  (one v_cos per element)
        float a0 = __fmaf_rn(z0[(2 * j + 0) * T_ + t], INV2PI_, MPHI);
        float a1 = __fmaf_rn(z0[(2 * j + 1) * T_ + t], INV2PI_, MPHI);
        v2f CO = {__builtin_amdgcn_cosf(a0), __builtin_amdgcn_cosf(a1)};
        v2f G = __builtin_elementwise_fma(CO, ADv, CNv);
        v2f R0 = {__builtin_amdgcn_exp2f(__builtin_amdgcn_exp2f(G.x) * E),
                  __builtin_amdgcn_exp2f(__builtin_amdgcn_exp2f(G.y) * E)};
        v2f R1 = {__builtin_amdgcn_exp2f(R[j].x), __builtin_amdgcn_exp2f(R[j].y)};
        v2f O = __builtin_elementwise_fma(W0, R0, W1 * R1);
        obase[(size_t)((2 * j + 0) * N + n) * T_ + t] = O.x;
        obase[(size_t)((2 * j + 1) * N + n) * T_ + t] = O.y;
    }
}

extern "C" void kernel_launch(void* const* d_in, const int* in_sizes, int n_in,
                              void* d_out, int out_size, void* d_ws, size_t ws_size,
                              hipStream_t stream) {
    const float* z0       = (const float*)d_in[0];
    const float* z1       = (const float*)d_in[1];
    const float* coeff0   = (const float*)d_in[2];
    const float* mean0    = (const float*)d_in[3];
    const float* log_var0 = (const float*)d_in[4];
    const float* coeff1   = (const float*)d_in[5];
    const float* mean1    = (const float*)d_in[6];
    const float* log_var1 = (const float*)d_in[7];
    const float* rf_tr0   = (const float*)d_in[8];
    const float* rf_tr1   = (const float*)d_in[9];
    const float* rf_te0   = (const float*)d_in[10];
    const float* rf_te1   = (const float*)d_in[11];
    const float* ew_tr    = (const float*)d_in[12];
    const float* ew_te    = (const float*)d_in[13];
    const float* lfs_tr   = (const float*)d_in[14];
    const float* lfs_te   = (const float*)d_in[15];
    float* out = (float*)d_out;

    int grid = NTR_ + NTE_;  // 1280 blocks, one per receptive field
    decoder_kernel<<<grid, T_, 0, stream>>>(
        z0, z1, coeff0, mean0, log_var0, coeff1, mean1, log_var1,
        rf_tr0, rf_tr1, rf_te0, rf_te1, ew_tr, ew_te, lfs_tr, lfs_te, out);
}